// Round 3
// baseline (2106.342 us; speedup 1.0000x reference)
//
#include <hip/hip_runtime.h>

#define Hh   128
#define Ww   128
#define Cc   512
#define NHh  16
#define Kk   7
#define Ss   9
#define HW   (Hh*Ww)          // 16384
#define Mtot (8*HW)           // 131072
#define KK2  (Kk*Kk)          // 49

typedef __attribute__((ext_vector_type(8))) short bf16x8;
typedef __attribute__((ext_vector_type(4))) float f32x4;

__device__ __forceinline__ unsigned short bf16_rn(float f) {
    union { float f; unsigned u; } v; v.f = f;
    unsigned r = v.u + 0x7fffu + ((v.u >> 16) & 1u);
    return (unsigned short)(r >> 16);
}
__device__ __forceinline__ float bf16_f32(unsigned short h) {
    union { unsigned u; float f; } v; v.u = ((unsigned)h) << 16; return v.f;
}

// ----------------------------------------------------------------------------
// split f32 -> (hi, lo) bf16.  n8 = n/8
// ----------------------------------------------------------------------------
__global__ __launch_bounds__(256) void split_kernel(const float* __restrict__ src,
                                                    unsigned short* __restrict__ dh,
                                                    unsigned short* __restrict__ dl,
                                                    int n8)
{
    for (int i = blockIdx.x * 256 + threadIdx.x; i < n8; i += gridDim.x * 256) {
        const float4* sp = (const float4*)src + (size_t)i * 2;
        const float4 a = sp[0], b = sp[1];
        const float vv[8] = {a.x, a.y, a.z, a.w, b.x, b.y, b.z, b.w};
        unsigned short h[8], l[8];
#pragma unroll
        for (int j = 0; j < 8; ++j) {
            h[j] = bf16_rn(vv[j]);
            l[j] = bf16_rn(vv[j] - bf16_f32(h[j]));
        }
        ushort4* dhp = (ushort4*)dh + (size_t)i * 2;
        ushort4* dlp = (ushort4*)dl + (size_t)i * 2;
        dhp[0] = make_ushort4(h[0], h[1], h[2], h[3]);
        dhp[1] = make_ushort4(h[4], h[5], h[6], h[7]);
        dlp[0] = make_ushort4(l[0], l[1], l[2], l[3]);
        dlp[1] = make_ushort4(l[4], l[5], l[6], l[7]);
    }
}

// ----------------------------------------------------------------------------
// C[M,512] = (Ah+Al)[M,512] @ (Wh+Wl)[512,512]^T + bias  (3-term bf16 split)
// (unchanged from round 2 — 128x128 tile, BK=32, global_load_lds, dbuf)
// ----------------------------------------------------------------------------
__global__ __launch_bounds__(256, 2) void gemm_split(
        const unsigned short* __restrict__ Ah, const unsigned short* __restrict__ Al,
        const unsigned short* __restrict__ Wh, const unsigned short* __restrict__ Wl,
        const float* __restrict__ bias, float* __restrict__ C)
{
    __shared__ char lds[65536];
    const int tid  = threadIdx.x;
    const int lane = tid & 63;
    const int w    = tid >> 6;
    const int wr   = w >> 1, wc = w & 1;

    const int id = ((blockIdx.x & 7) << 9) + (blockIdx.x >> 3);
    const int m0 = (id >> 2) << 7;
    const int n0 = (id & 3) << 7;

    const unsigned short* tb = (w == 0) ? Ah : (w == 1) ? Al : (w == 2) ? Wh : Wl;
    const int row0 = (w < 2) ? m0 : n0;
    const char* gl = (const char*)tb + ((size_t)(row0 + lane)) * 1024;

    f32x4 acc[4][4];
#pragma unroll
    for (int a = 0; a < 4; ++a)
#pragma unroll
        for (int b = 0; b < 4; ++b) acc[a][b] = (f32x4)0.f;

#pragma unroll
    for (int q = 0; q < 8; ++q)
        __builtin_amdgcn_global_load_lds(
            (const __attribute__((address_space(1))) void*)(gl + (q & 1) * 65536 + (q >> 1) * 16),
            (__attribute__((address_space(3))) void*)(&lds[w * 8192] + q * 1024), 16, 0, 0);
    __syncthreads();

    const int laneoff = ((lane >> 4) << 11) + ((lane & 15) << 4);
    const int aoff = laneoff + wr * 1024;
    const int boff = laneoff + wc * 1024;

    for (int kt = 0; kt < 16; ++kt) {
        const int cur = kt & 1;
        if (kt < 15) {
            const char* gn = gl + (kt + 1) * 64;
            char* dst = &lds[(cur ^ 1) * 32768 + w * 8192];
#pragma unroll
            for (int q = 0; q < 8; ++q)
                __builtin_amdgcn_global_load_lds(
                    (const __attribute__((address_space(1))) void*)(gn + (q & 1) * 65536 + (q >> 1) * 16),
                    (__attribute__((address_space(3))) void*)(dst + q * 1024), 16, 0, 0);
        }
        const char* LA = &lds[cur * 32768];
        bf16x8 ah[4], alo[4], bh[4], blo[4];
#pragma unroll
        for (int mf = 0; mf < 4; ++mf) {
            ah[mf]  = *(const bf16x8*)(LA + aoff + mf * 256);
            alo[mf] = *(const bf16x8*)(LA + 8192 + aoff + mf * 256);
        }
#pragma unroll
        for (int nf = 0; nf < 4; ++nf) {
            bh[nf]  = *(const bf16x8*)(LA + 16384 + boff + nf * 256);
            blo[nf] = *(const bf16x8*)(LA + 24576 + boff + nf * 256);
        }
#pragma unroll
        for (int mi = 0; mi < 4; ++mi)
#pragma unroll
            for (int ni = 0; ni < 4; ++ni) {
                acc[mi][ni] = __builtin_amdgcn_mfma_f32_16x16x32_bf16(ah[mi],  bh[ni],  acc[mi][ni], 0, 0, 0);
                acc[mi][ni] = __builtin_amdgcn_mfma_f32_16x16x32_bf16(ah[mi],  blo[ni], acc[mi][ni], 0, 0, 0);
                acc[mi][ni] = __builtin_amdgcn_mfma_f32_16x16x32_bf16(alo[mi], bh[ni],  acc[mi][ni], 0, 0, 0);
            }
        __syncthreads();
    }

    const int crow = (lane >> 4) << 2;
    const int ccol = lane & 15;
#pragma unroll
    for (int ni = 0; ni < 4; ++ni) {
        const int col = n0 + wc * 64 + ni * 16 + ccol;
        const float bv = bias[col];
#pragma unroll
        for (int mi = 0; mi < 4; ++mi) {
            float* cp = C + (size_t)(m0 + wr * 64 + mi * 16 + crow) * 512 + col;
            cp[0]    = acc[mi][ni][0] + bv;
            cp[512]  = acc[mi][ni][1] + bv;
            cp[1024] = acc[mi][ni][2] + bv;
            cp[1536] = acc[mi][ni][3] + bv;
        }
    }
}

// ----------------------------------------------------------------------------
// wgt[pix][k] (unchanged)
// ----------------------------------------------------------------------------
__global__ __launch_bounds__(256) void wgt_kernel(const float* __restrict__ sims,
                                                  const int* __restrict__ sinds,
                                                  float* __restrict__ wgt)
{
    const int pix = blockIdx.x * 256 + threadIdx.x;
    const int b  = pix >> 14;
    const int ij = pix & 16383;
    const int i  = ij >> 7;
    const int j  = ij & 127;

    float os[Ss]; int oi[Ss];
    const float* sp = sims + (size_t)pix * Ss;
    const int*   ip = sinds + (size_t)pix * Ss;
#pragma unroll
    for (int s = 0; s < Ss; ++s) { os[s] = sp[s]; oi[s] = ip[s]; }

    const int si = min(max(i - 3, 0), Hh - Kk);
    const int sj = min(max(j - 3, 0), Ww - Kk);
    float* wp = wgt + (size_t)pix * KK2;

    int kidx = 0;
    for (int ki = 0; ki < Kk; ++ki) {
        const int ni = si + ki;
        for (int kj = 0; kj < Kk; ++kj, ++kidx) {
            const int nj = sj + kj;
            const int npix = (b << 14) + (ni << 7) + nj;
            const float* nsp = sims + (size_t)npix * Ss;
            const int*   nip = sinds + (size_t)npix * Ss;
            float acc = 0.f;
#pragma unroll
            for (int t = 0; t < Ss; ++t) {
                const int   nid = nip[t];
                const float nsm = nsp[t];
                float m = 0.f;
#pragma unroll
                for (int s = 0; s < Ss; ++s) m += (oi[s] == nid) ? os[s] : 0.f;
                acc += m * nsm;
            }
            wp[kidx] = acc;
        }
    }
}

// ----------------------------------------------------------------------------
// aggregation, 16-pixel row tiles.
// block = 16 consecutive pixels (same row), 128 threads (thread = 4 channels,
// nh = tid>>3). v neighborhood row (22 cols x float4) held in registers,
// reused by all 16 pixels. coef = attn*wgt in LDS [16p][16nh][50] f32
// (50-pad -> per-(p,kj) read has 8 distinct banks per wave, conflict-free).
// Static vr indexing via 3 edge variants: idx = p+kj+d(p), d constexpr per
// unrolled p. XCD-chunked swizzle: each XCD owns one image (v slice stays L2).
// ----------------------------------------------------------------------------
template<int VAR>   // 0 = interior, 1 = left edge (j0==0), 2 = right edge (j0==112)
__device__ __forceinline__ void agg_rows(const float* __restrict__ vbase,
                                         const float* __restrict__ coef,
                                         int si, int cb, int nh, f32x4 acc[16])
{
    for (int ki = 0; ki < Kk; ++ki) {
        const float* vrowp = vbase + (size_t)(si + ki) * (Ww * Cc) + (size_t)cb * Cc;
        float4 vr[22];
#pragma unroll
        for (int c = 0; c < 22; ++c) vr[c] = *(const float4*)(vrowp + c * Cc);
        const float* cpk = coef + nh * 50 + ki * 7;
#pragma unroll
        for (int p = 0; p < 16; ++p) {
            const int d = (VAR == 0) ? 0
                        : (VAR == 1) ? -((p < 3) ? p : 3)
                                     : (3 - ((p > 12) ? (p - 12) : 0));
#pragma unroll
            for (int kj = 0; kj < 7; ++kj) {
                const float  cf = cpk[p * 800 + kj];
                const float4 vv = vr[p + kj + d];
                acc[p][0] += cf * vv.x;
                acc[p][1] += cf * vv.y;
                acc[p][2] += cf * vv.z;
                acc[p][3] += cf * vv.w;
            }
        }
    }
}

__global__ __launch_bounds__(128) void agg_kernel(const float* __restrict__ v,
                                                  const float* __restrict__ attn,
                                                  const float* __restrict__ wgt,
                                                  unsigned short* __restrict__ oh,
                                                  unsigned short* __restrict__ ol)
{
    // 8192 blocks; XCD chunk: XCD x -> image x, row-major tile sweep
    const int t   = ((blockIdx.x & 7) << 10) | (blockIdx.x >> 3);
    const int b   = t >> 10;
    const int rem = t & 1023;
    const int i   = rem >> 3;
    const int j0  = (rem & 7) << 4;
    const int tid = threadIdx.x;
    const int nh  = tid >> 3;

    __shared__ float coef[16 * 16 * 50];    // [p][nh][50k], 51.2 KB

    const int pixbase = (b << 14) | (i << 7) | j0;
    // build coef[p][h][k] = attn[b,h,i,j0+p,k] * wgt[pixbase+p,k]
    for (int e = tid; e < 16 * 16 * KK2; e += 128) {
        const int p = e / (16 * KK2);
        const int r = e - p * (16 * KK2);
        const int h = r / KK2;
        const int k = r - h * KK2;
        const size_t aidx = ((size_t)(b * NHh + h) * HW + (size_t)((i << 7) | (j0 + p))) * KK2 + k;
        coef[(p * 16 + h) * 50 + k] = attn[aidx] * wgt[(size_t)(pixbase + p) * KK2 + k];
    }

    f32x4 acc[16];
#pragma unroll
    for (int p = 0; p < 16; ++p) acc[p] = (f32x4)0.f;

    const int si = min(max(i - 3, 0), Hh - Kk);
    const int cb = min(max(j0 - 3, 0), Ww - 22);
    const float* vbase = v + ((size_t)b << 23) + (size_t)(tid << 2);

    __syncthreads();

    if (j0 == 0)            agg_rows<1>(vbase, coef, si, cb, nh, acc);
    else if (j0 == 112)     agg_rows<2>(vbase, coef, si, cb, nh, acc);
    else                    agg_rows<0>(vbase, coef, si, cb, nh, acc);

#pragma unroll
    for (int p = 0; p < 16; ++p) {
        const size_t o = (size_t)(pixbase + p) * Cc + (size_t)(tid << 2);
        const unsigned short h0 = bf16_rn(acc[p][0]), h1 = bf16_rn(acc[p][1]),
                             h2 = bf16_rn(acc[p][2]), h3 = bf16_rn(acc[p][3]);
        *(ushort4*)(oh + o) = make_ushort4(h0, h1, h2, h3);
        *(ushort4*)(ol + o) = make_ushort4(bf16_rn(acc[p][0] - bf16_f32(h0)),
                                           bf16_rn(acc[p][1] - bf16_f32(h1)),
                                           bf16_rn(acc[p][2] - bf16_f32(h2)),
                                           bf16_rn(acc[p][3] - bf16_f32(h3)));
    }
}

// ----------------------------------------------------------------------------
extern "C" void kernel_launch(void* const* d_in, const int* in_sizes, int n_in,
                              void* d_out, int out_size, void* d_ws, size_t ws_size,
                              hipStream_t stream)
{
    const float* x      = (const float*)d_in[0];
    const float* attn   = (const float*)d_in[1];
    const float* sims   = (const float*)d_in[2];
    const int*   sinds  = (const int*)d_in[3];
    const float* v_w    = (const float*)d_in[4];
    const float* v_b    = (const float*)d_in[5];
    const float* proj_w = (const float*)d_in[6];
    const float* proj_b = (const float*)d_in[7];
    float* out = (float*)d_out;

    char* ws = (char*)d_ws;
    float*          v   = (float*)ws;                                   // 268 MB
    unsigned short* xh  = (unsigned short*)(ws + 268435456);            // 134 MB
    unsigned short* xl  = (unsigned short*)(ws + 268435456 + 134217728);// 134 MB
    float*          wgt = (float*)(ws + 536870912);                     // 25.7 MB
    unsigned short* vwh = (unsigned short*)(ws + 536870912 + 25690112);
    unsigned short* vwl = vwh + 262144;
    unsigned short* pwh = vwl + 262144;
    unsigned short* pwl = pwh + 262144;
    unsigned short* aggh = xh;   // x dead after gemm1
    unsigned short* aggl = xl;

    split_kernel<<<2048, 256, 0, stream>>>(x, xh, xl, Mtot * 512 / 8);
    split_kernel<<<128, 256, 0, stream>>>(v_w, vwh, vwl, 262144 / 8);
    split_kernel<<<128, 256, 0, stream>>>(proj_w, pwh, pwl, 262144 / 8);

    gemm_split<<<4096, 256, 0, stream>>>(xh, xl, vwh, vwl, v_b, v);
    wgt_kernel<<<512, 256, 0, stream>>>(sims, sinds, wgt);
    agg_kernel<<<8192, 128, 0, stream>>>(v, attn, wgt, aggh, aggl);
    gemm_split<<<4096, 256, 0, stream>>>(aggh, aggl, pwh, pwl, proj_b, out);
}

// Round 4
// 1984.061 us; speedup vs baseline: 1.0616x; 1.0616x over previous
//
#include <hip/hip_runtime.h>

#define Hh   128
#define Ww   128
#define Cc   512
#define NHh  16
#define Kk   7
#define Ss   9
#define HW   (Hh*Ww)          // 16384
#define Mtot (8*HW)           // 131072
#define KK2  (Kk*Kk)          // 49

typedef __attribute__((ext_vector_type(8))) short bf16x8;
typedef __attribute__((ext_vector_type(4))) float f32x4;

__device__ __forceinline__ unsigned short bf16_rn(float f) {
    union { float f; unsigned u; } v; v.f = f;
    unsigned r = v.u + 0x7fffu + ((v.u >> 16) & 1u);
    return (unsigned short)(r >> 16);
}
__device__ __forceinline__ float bf16_f32(unsigned short h) {
    union { unsigned u; float f; } v; v.u = ((unsigned)h) << 16; return v.f;
}

// ----------------------------------------------------------------------------
// split f32 -> (hi, lo) bf16.  n8 = n/8
// ----------------------------------------------------------------------------
__global__ __launch_bounds__(256) void split_kernel(const float* __restrict__ src,
                                                    unsigned short* __restrict__ dh,
                                                    unsigned short* __restrict__ dl,
                                                    int n8)
{
    for (int i = blockIdx.x * 256 + threadIdx.x; i < n8; i += gridDim.x * 256) {
        const float4* sp = (const float4*)src + (size_t)i * 2;
        const float4 a = sp[0], b = sp[1];
        const float vv[8] = {a.x, a.y, a.z, a.w, b.x, b.y, b.z, b.w};
        unsigned short h[8], l[8];
#pragma unroll
        for (int j = 0; j < 8; ++j) {
            h[j] = bf16_rn(vv[j]);
            l[j] = bf16_rn(vv[j] - bf16_f32(h[j]));
        }
        ushort4* dhp = (ushort4*)dh + (size_t)i * 2;
        ushort4* dlp = (ushort4*)dl + (size_t)i * 2;
        dhp[0] = make_ushort4(h[0], h[1], h[2], h[3]);
        dhp[1] = make_ushort4(h[4], h[5], h[6], h[7]);
        dlp[0] = make_ushort4(l[0], l[1], l[2], l[3]);
        dlp[1] = make_ushort4(l[4], l[5], l[6], l[7]);
    }
}

// ----------------------------------------------------------------------------
// C[M,512] = (Ah+Al)[M,512] @ (Wh+Wl)[512,512]^T + bias  (3-term bf16 split)
// (unchanged from round 2)
// ----------------------------------------------------------------------------
__global__ __launch_bounds__(256, 2) void gemm_split(
        const unsigned short* __restrict__ Ah, const unsigned short* __restrict__ Al,
        const unsigned short* __restrict__ Wh, const unsigned short* __restrict__ Wl,
        const float* __restrict__ bias, float* __restrict__ C)
{
    __shared__ char lds[65536];
    const int tid  = threadIdx.x;
    const int lane = tid & 63;
    const int w    = tid >> 6;
    const int wr   = w >> 1, wc = w & 1;

    const int id = ((blockIdx.x & 7) << 9) + (blockIdx.x >> 3);
    const int m0 = (id >> 2) << 7;
    const int n0 = (id & 3) << 7;

    const unsigned short* tb = (w == 0) ? Ah : (w == 1) ? Al : (w == 2) ? Wh : Wl;
    const int row0 = (w < 2) ? m0 : n0;
    const char* gl = (const char*)tb + ((size_t)(row0 + lane)) * 1024;

    f32x4 acc[4][4];
#pragma unroll
    for (int a = 0; a < 4; ++a)
#pragma unroll
        for (int b = 0; b < 4; ++b) acc[a][b] = (f32x4)0.f;

#pragma unroll
    for (int q = 0; q < 8; ++q)
        __builtin_amdgcn_global_load_lds(
            (const __attribute__((address_space(1))) void*)(gl + (q & 1) * 65536 + (q >> 1) * 16),
            (__attribute__((address_space(3))) void*)(&lds[w * 8192] + q * 1024), 16, 0, 0);
    __syncthreads();

    const int laneoff = ((lane >> 4) << 11) + ((lane & 15) << 4);
    const int aoff = laneoff + wr * 1024;
    const int boff = laneoff + wc * 1024;

    for (int kt = 0; kt < 16; ++kt) {
        const int cur = kt & 1;
        if (kt < 15) {
            const char* gn = gl + (kt + 1) * 64;
            char* dst = &lds[(cur ^ 1) * 32768 + w * 8192];
#pragma unroll
            for (int q = 0; q < 8; ++q)
                __builtin_amdgcn_global_load_lds(
                    (const __attribute__((address_space(1))) void*)(gn + (q & 1) * 65536 + (q >> 1) * 16),
                    (__attribute__((address_space(3))) void*)(dst + q * 1024), 16, 0, 0);
        }
        const char* LA = &lds[cur * 32768];
        bf16x8 ah[4], alo[4], bh[4], blo[4];
#pragma unroll
        for (int mf = 0; mf < 4; ++mf) {
            ah[mf]  = *(const bf16x8*)(LA + aoff + mf * 256);
            alo[mf] = *(const bf16x8*)(LA + 8192 + aoff + mf * 256);
        }
#pragma unroll
        for (int nf = 0; nf < 4; ++nf) {
            bh[nf]  = *(const bf16x8*)(LA + 16384 + boff + nf * 256);
            blo[nf] = *(const bf16x8*)(LA + 24576 + boff + nf * 256);
        }
#pragma unroll
        for (int mi = 0; mi < 4; ++mi)
#pragma unroll
            for (int ni = 0; ni < 4; ++ni) {
                acc[mi][ni] = __builtin_amdgcn_mfma_f32_16x16x32_bf16(ah[mi],  bh[ni],  acc[mi][ni], 0, 0, 0);
                acc[mi][ni] = __builtin_amdgcn_mfma_f32_16x16x32_bf16(ah[mi],  blo[ni], acc[mi][ni], 0, 0, 0);
                acc[mi][ni] = __builtin_amdgcn_mfma_f32_16x16x32_bf16(alo[mi], bh[ni],  acc[mi][ni], 0, 0, 0);
            }
        __syncthreads();
    }

    const int crow = (lane >> 4) << 2;
    const int ccol = lane & 15;
#pragma unroll
    for (int ni = 0; ni < 4; ++ni) {
        const int col = n0 + wc * 64 + ni * 16 + ccol;
        const float bv = bias[col];
#pragma unroll
        for (int mi = 0; mi < 4; ++mi) {
            float* cp = C + (size_t)(m0 + wr * 64 + mi * 16 + crow) * 512 + col;
            cp[0]    = acc[mi][ni][0] + bv;
            cp[512]  = acc[mi][ni][1] + bv;
            cp[1024] = acc[mi][ni][2] + bv;
            cp[1536] = acc[mi][ni][3] + bv;
        }
    }
}

// ----------------------------------------------------------------------------
// wgt[pix][k] (unchanged)
// ----------------------------------------------------------------------------
__global__ __launch_bounds__(256) void wgt_kernel(const float* __restrict__ sims,
                                                  const int* __restrict__ sinds,
                                                  float* __restrict__ wgt)
{
    const int pix = blockIdx.x * 256 + threadIdx.x;
    const int b  = pix >> 14;
    const int ij = pix & 16383;
    const int i  = ij >> 7;
    const int j  = ij & 127;

    float os[Ss]; int oi[Ss];
    const float* sp = sims + (size_t)pix * Ss;
    const int*   ip = sinds + (size_t)pix * Ss;
#pragma unroll
    for (int s = 0; s < Ss; ++s) { os[s] = sp[s]; oi[s] = ip[s]; }

    const int si = min(max(i - 3, 0), Hh - Kk);
    const int sj = min(max(j - 3, 0), Ww - Kk);
    float* wp = wgt + (size_t)pix * KK2;

    int kidx = 0;
    for (int ki = 0; ki < Kk; ++ki) {
        const int ni = si + ki;
        for (int kj = 0; kj < Kk; ++kj, ++kidx) {
            const int nj = sj + kj;
            const int npix = (b << 14) + (ni << 7) + nj;
            const float* nsp = sims + (size_t)npix * Ss;
            const int*   nip = sinds + (size_t)npix * Ss;
            float acc = 0.f;
#pragma unroll
            for (int t = 0; t < Ss; ++t) {
                const int   nid = nip[t];
                const float nsm = nsp[t];
                float m = 0.f;
#pragma unroll
                for (int s = 0; s < Ss; ++s) m += (oi[s] == nid) ? os[s] : 0.f;
                acc += m * nsm;
            }
            wp[kidx] = acc;
        }
    }
}

// ----------------------------------------------------------------------------
// aggregation, 8-pixel row tiles (occupancy-fixed rework of round 3).
// block = 8 consecutive pixels (same row), 128 threads, thread = 4 channels,
// nh = tid>>3. v window row (14 cols x float4) in registers, reused by all
// 8 pixels. coef LDS [8p][16nh][51] f32 = 25.5 KB -> 6 blocks/CU (12 waves).
// stride 51: 19n mod 32 bijective -> write phase 2-way (free), read broadcast.
// ----------------------------------------------------------------------------
template<int VAR>   // 0 = interior, 1 = left edge (j0==0), 2 = right edge (j0==120)
__device__ __forceinline__ void agg_rows(const float* __restrict__ vbase,
                                         const float* __restrict__ coef,
                                         int si, int nh, f32x4 acc[8])
{
    const float* cbase = coef + nh * 51;
#pragma unroll
    for (int ki = 0; ki < Kk; ++ki) {
        const float* vrowp = vbase + (size_t)(si + ki) * (Ww * Cc);
        float4 vr[14];
#pragma unroll
        for (int c = 0; c < 14; ++c) vr[c] = *(const float4*)(vrowp + c * Cc);
        const float* cpk = cbase + ki * 7;
#pragma unroll
        for (int p = 0; p < 8; ++p) {
            const int d = (VAR == 0) ? 0
                        : (VAR == 1) ? -((p < 3) ? p : 3)
                                     : (3 - ((p > 4) ? (p - 4) : 0));
#pragma unroll
            for (int kj = 0; kj < 7; ++kj) {
                const float  cf = cpk[p * (16 * 51) + kj];
                const float4 vv = vr[p + kj + d];
                acc[p][0] += cf * vv.x;
                acc[p][1] += cf * vv.y;
                acc[p][2] += cf * vv.z;
                acc[p][3] += cf * vv.w;
            }
        }
    }
}

__global__ __launch_bounds__(128, 3) void agg_kernel(const float* __restrict__ v,
                                                     const float* __restrict__ attn,
                                                     const float* __restrict__ wgt,
                                                     unsigned short* __restrict__ oh,
                                                     unsigned short* __restrict__ ol)
{
    // 16384 blocks; XCD x owns image x (v slice 268MB/8 per-row working set
    // ~1.3MB stays in that XCD's L2), row-major tile sweep within image.
    const int t   = ((blockIdx.x & 7) << 11) | (blockIdx.x >> 3);
    const int b   = t >> 11;
    const int rem = t & 2047;
    const int i   = rem >> 4;
    const int j0  = (rem & 15) << 3;
    const int tid = threadIdx.x;
    const int nh  = tid >> 3;

    __shared__ float coef[8 * 16 * 51];    // 25.5 KB

    const int pixbase = (b << 14) | (i << 7) | j0;
    for (int e = tid; e < 8 * 16 * KK2; e += 128) {
        const int p = e / (16 * KK2);
        const int r = e - p * (16 * KK2);
        const int h = r / KK2;
        const int k = r - h * KK2;
        coef[(p * 16 + h) * 51 + k] =
            attn[((size_t)(b * NHh + h) * HW + (size_t)((i << 7) | (j0 + p))) * KK2 + k]
            * wgt[(size_t)(pixbase + p) * KK2 + k];
    }

    f32x4 acc[8];
#pragma unroll
    for (int p = 0; p < 8; ++p) acc[p] = (f32x4)0.f;

    const int si = min(max(i - 3, 0), Hh - Kk);
    const int cb = (j0 == 0) ? 0 : ((j0 == 120) ? (Ww - 14) : (j0 - 3));
    const float* vbase = v + ((size_t)b << 23) + ((size_t)cb << 9) + (tid << 2);

    __syncthreads();

    if (j0 == 0)            agg_rows<1>(vbase, coef, si, nh, acc);
    else if (j0 == 120)     agg_rows<2>(vbase, coef, si, nh, acc);
    else                    agg_rows<0>(vbase, coef, si, nh, acc);

#pragma unroll
    for (int p = 0; p < 8; ++p) {
        const size_t o = (size_t)(pixbase + p) * Cc + (size_t)(tid << 2);
        const unsigned short h0 = bf16_rn(acc[p][0]), h1 = bf16_rn(acc[p][1]),
                             h2 = bf16_rn(acc[p][2]), h3 = bf16_rn(acc[p][3]);
        *(ushort4*)(oh + o) = make_ushort4(h0, h1, h2, h3);
        *(ushort4*)(ol + o) = make_ushort4(bf16_rn(acc[p][0] - bf16_f32(h0)),
                                           bf16_rn(acc[p][1] - bf16_f32(h1)),
                                           bf16_rn(acc[p][2] - bf16_f32(h2)),
                                           bf16_rn(acc[p][3] - bf16_f32(h3)));
    }
}

// ----------------------------------------------------------------------------
extern "C" void kernel_launch(void* const* d_in, const int* in_sizes, int n_in,
                              void* d_out, int out_size, void* d_ws, size_t ws_size,
                              hipStream_t stream)
{
    const float* x      = (const float*)d_in[0];
    const float* attn   = (const float*)d_in[1];
    const float* sims   = (const float*)d_in[2];
    const int*   sinds  = (const int*)d_in[3];
    const float* v_w    = (const float*)d_in[4];
    const float* v_b    = (const float*)d_in[5];
    const float* proj_w = (const float*)d_in[6];
    const float* proj_b = (const float*)d_in[7];
    float* out = (float*)d_out;

    char* ws = (char*)d_ws;
    float*          v   = (float*)ws;                                   // 268 MB
    unsigned short* xh  = (unsigned short*)(ws + 268435456);            // 134 MB
    unsigned short* xl  = (unsigned short*)(ws + 268435456 + 134217728);// 134 MB
    float*          wgt = (float*)(ws + 536870912);                     // 25.7 MB
    unsigned short* vwh = (unsigned short*)(ws + 536870912 + 25690112);
    unsigned short* vwl = vwh + 262144;
    unsigned short* pwh = vwl + 262144;
    unsigned short* pwl = pwh + 262144;
    unsigned short* aggh = xh;   // x dead after gemm1
    unsigned short* aggl = xl;

    split_kernel<<<2048, 256, 0, stream>>>(x, xh, xl, Mtot * 512 / 8);
    split_kernel<<<128, 256, 0, stream>>>(v_w, vwh, vwl, 262144 / 8);
    split_kernel<<<128, 256, 0, stream>>>(proj_w, pwh, pwl, 262144 / 8);

    gemm_split<<<4096, 256, 0, stream>>>(xh, xl, vwh, vwl, v_b, v);
    wgt_kernel<<<512, 256, 0, stream>>>(sims, sinds, wgt);
    agg_kernel<<<16384, 128, 0, stream>>>(v, attn, wgt, aggh, aggl);
    gemm_split<<<4096, 256, 0, stream>>>(aggh, aggl, pwh, pwl, proj_b, out);
}

// Round 6
// 1565.260 us; speedup vs baseline: 1.3457x; 1.2676x over previous
//
#include <hip/hip_runtime.h>

#define Hh   128
#define Ww   128
#define Cc   512
#define NHh  16
#define Kk   7
#define Ss   9
#define HW   (Hh*Ww)          // 16384
#define Mtot (8*HW)           // 131072
#define KK2  (Kk*Kk)          // 49

typedef __attribute__((ext_vector_type(8))) short bf16x8;
typedef __attribute__((ext_vector_type(4))) float f32x4;
typedef __attribute__((ext_vector_type(4))) unsigned short u16x4;

#define AS1 __attribute__((address_space(1)))
#define AS3 __attribute__((address_space(3)))

__device__ __forceinline__ unsigned short bf16_rn(float f) {
    union { float f; unsigned u; } v; v.f = f;
    unsigned r = v.u + 0x7fffu + ((v.u >> 16) & 1u);
    return (unsigned short)(r >> 16);
}
__device__ __forceinline__ float bf16_f32(unsigned short h) {
    union { unsigned u; float f; } v; v.u = ((unsigned)h) << 16; return v.f;
}

// ----------------------------------------------------------------------------
// split f32 -> (hi, lo) bf16.  n8 = n/8  (unchanged)
// ----------------------------------------------------------------------------
__global__ __launch_bounds__(256) void split_kernel(const float* __restrict__ src,
                                                    unsigned short* __restrict__ dh,
                                                    unsigned short* __restrict__ dl,
                                                    int n8)
{
    for (int i = blockIdx.x * 256 + threadIdx.x; i < n8; i += gridDim.x * 256) {
        const float4* sp = (const float4*)src + (size_t)i * 2;
        const float4 a = sp[0], b = sp[1];
        const float vv[8] = {a.x, a.y, a.z, a.w, b.x, b.y, b.z, b.w};
        unsigned short h[8], l[8];
#pragma unroll
        for (int j = 0; j < 8; ++j) {
            h[j] = bf16_rn(vv[j]);
            l[j] = bf16_rn(vv[j] - bf16_f32(h[j]));
        }
        ushort4* dhp = (ushort4*)dh + (size_t)i * 2;
        ushort4* dlp = (ushort4*)dl + (size_t)i * 2;
        dhp[0] = make_ushort4(h[0], h[1], h[2], h[3]);
        dhp[1] = make_ushort4(h[4], h[5], h[6], h[7]);
        dlp[0] = make_ushort4(l[0], l[1], l[2], l[3]);
        dlp[1] = make_ushort4(l[4], l[5], l[6], l[7]);
    }
}

// ----------------------------------------------------------------------------
// Concat-K split GEMM: C[M,512] = sum_t A_t[M,512] @ B_t[512,512]^T + bias
// over virtual K=1536: kt -> (t=kt%3, kb=kt/3); A = t<2?Ah:Al, B = t==1?Wl:Wh.
// 128x128 tile, BK=32, 4 waves (wave quadrant 64x64), dbuf LDS 2x16KB,
// global_load_lds width-16, 8 ds_read_b128 + 16 MFMA per kt.
// launch_bounds(256,4): VGPR<=128 -> 4 blocks/CU = 16 waves (latency hiding).
// ----------------------------------------------------------------------------
template<bool NT>
__global__ __launch_bounds__(256, 4) void gemm_c3(
        const unsigned short* __restrict__ Ah, const unsigned short* __restrict__ Al,
        const unsigned short* __restrict__ Wh, const unsigned short* __restrict__ Wl,
        const float* __restrict__ bias, float* __restrict__ C)
{
    __shared__ char lds[32768];             // 2 buffers x (A 8KB + B 8KB)
    const int tid  = threadIdx.x;
    const int lane = tid & 63;
    const int w    = tid >> 6;
    const int wr   = w >> 1, wc = w & 1;

    // XCD-chunked swizzle: 4 n-blocks of an m-panel stay on one XCD
    const int id = ((blockIdx.x & 7) << 9) + (blockIdx.x >> 3);
    const int m0 = (id >> 2) << 7;
    const int n0 = (id & 3) << 7;

    // staging: chunk c = q*4+w covers rows c*16..c*16+15 of the 128-row tile;
    // lane covers row c*16 + (lane>>2), bytes (lane&3)*16 of the 64B k-row.
    const size_t aRow = (size_t)(m0 + w * 16 + (lane >> 2)) * 1024 + ((lane & 3) << 4);
    const size_t bRow = (size_t)(n0 + w * 16 + (lane >> 2)) * 1024 + ((lane & 3) << 4);

    f32x4 acc[4][4];
#pragma unroll
    for (int a = 0; a < 4; ++a)
#pragma unroll
        for (int b = 0; b < 4; ++b) acc[a][b] = (f32x4)0.f;

    // fragment ds_read offsets (row-major [128][32] bf16, 64B rows)
    const int aoffL = (wr * 64 + (lane & 15)) * 64 + ((lane >> 4) << 4);
    const int boffL = 8192 + (wc * 64 + (lane & 15)) * 64 + ((lane >> 4) << 4);

    // prologue: stage kt=0 (t=0,kb=0: Ah x Wh) into buffer 0
#pragma unroll
    for (int q = 0; q < 2; ++q) {
        __builtin_amdgcn_global_load_lds(
            (const AS1 void*)((const char*)Ah + aRow + (size_t)q * 65536),
            (AS3 void*)(&lds[(q * 4 + w) * 1024]), 16, 0, 0);
        __builtin_amdgcn_global_load_lds(
            (const AS1 void*)((const char*)Wh + bRow + (size_t)q * 65536),
            (AS3 void*)(&lds[8192 + (q * 4 + w) * 1024]), 16, 0, 0);
    }
    __syncthreads();

    int tn = 1, kbn = 0;    // (t, kb) of the NEXT kt to stage
    for (int kt = 0; kt < 48; ++kt) {
        const int cur = kt & 1;
        if (kt < 47) {
            const char* Ap = (const char*)((tn < 2) ? Ah : Al) + (size_t)kbn * 64;
            const char* Bp = (const char*)((tn == 1) ? Wl : Wh) + (size_t)kbn * 64;
            char* dst = &lds[(cur ^ 1) * 16384];
#pragma unroll
            for (int q = 0; q < 2; ++q) {
                __builtin_amdgcn_global_load_lds(
                    (const AS1 void*)(Ap + aRow + (size_t)q * 65536),
                    (AS3 void*)(dst + (q * 4 + w) * 1024), 16, 0, 0);
                __builtin_amdgcn_global_load_lds(
                    (const AS1 void*)(Bp + bRow + (size_t)q * 65536),
                    (AS3 void*)(dst + 8192 + (q * 4 + w) * 1024), 16, 0, 0);
            }
            if (++tn == 3) { tn = 0; ++kbn; }
        }
        const char* LA = &lds[cur * 16384];
        bf16x8 a[4], b[4];
#pragma unroll
        for (int mi = 0; mi < 4; ++mi) a[mi] = *(const bf16x8*)(LA + aoffL + mi * 1024);
#pragma unroll
        for (int ni = 0; ni < 4; ++ni) b[ni] = *(const bf16x8*)(LA + boffL + ni * 1024);
#pragma unroll
        for (int mi = 0; mi < 4; ++mi)
#pragma unroll
            for (int ni = 0; ni < 4; ++ni)
                acc[mi][ni] = __builtin_amdgcn_mfma_f32_16x16x32_bf16(a[mi], b[ni], acc[mi][ni], 0, 0, 0);
        __syncthreads();
    }

    const int crow = (lane >> 4) << 2;
    const int ccol = lane & 15;
#pragma unroll
    for (int ni = 0; ni < 4; ++ni) {
        const int col = n0 + wc * 64 + ni * 16 + ccol;
        const float bv = bias[col];
#pragma unroll
        for (int mi = 0; mi < 4; ++mi) {
            float* cp = C + (size_t)(m0 + wr * 64 + mi * 16 + crow) * 512 + col;
#pragma unroll
            for (int r = 0; r < 4; ++r) {
                const float val = acc[mi][ni][r] + bv;
                if (NT) __builtin_nontemporal_store(val, cp + (size_t)r * 512);
                else    cp[(size_t)r * 512] = val;
            }
        }
    }
}

// ----------------------------------------------------------------------------
// wgt[pix][k] (unchanged)
// ----------------------------------------------------------------------------
__global__ __launch_bounds__(256) void wgt_kernel(const float* __restrict__ sims,
                                                  const int* __restrict__ sinds,
                                                  float* __restrict__ wgt)
{
    const int pix = blockIdx.x * 256 + threadIdx.x;
    const int b  = pix >> 14;
    const int ij = pix & 16383;
    const int i  = ij >> 7;
    const int j  = ij & 127;

    float os[Ss]; int oi[Ss];
    const float* sp = sims + (size_t)pix * Ss;
    const int*   ip = sinds + (size_t)pix * Ss;
#pragma unroll
    for (int s = 0; s < Ss; ++s) { os[s] = sp[s]; oi[s] = ip[s]; }

    const int si = min(max(i - 3, 0), Hh - Kk);
    const int sj = min(max(j - 3, 0), Ww - Kk);
    float* wp = wgt + (size_t)pix * KK2;

    int kidx = 0;
    for (int ki = 0; ki < Kk; ++ki) {
        const int ni = si + ki;
        for (int kj = 0; kj < Kk; ++kj, ++kidx) {
            const int nj = sj + kj;
            const int npix = (b << 14) + (ni << 7) + nj;
            const float* nsp = sims + (size_t)npix * Ss;
            const int*   nip = sinds + (size_t)npix * Ss;
            float acc = 0.f;
#pragma unroll
            for (int t = 0; t < Ss; ++t) {
                const int   nid = nip[t];
                const float nsm = nsp[t];
                float m = 0.f;
#pragma unroll
                for (int s = 0; s < Ss; ++s) m += (oi[s] == nid) ? os[s] : 0.f;
                acc += m * nsm;
            }
            wp[kidx] = acc;
        }
    }
}

// ----------------------------------------------------------------------------
// aggregation, 8-pixel row tiles (round-4 structure + nontemporal attn loads
// and nontemporal hi/lo stores: read-once / write-once data, keep v in L2)
// ----------------------------------------------------------------------------
template<int VAR>   // 0 = interior, 1 = left edge (j0==0), 2 = right edge (j0==120)
__device__ __forceinline__ void agg_rows(const float* __restrict__ vbase,
                                         const float* __restrict__ coef,
                                         int si, int nh, f32x4 acc[8])
{
    const float* cbase = coef + nh * 51;
#pragma unroll
    for (int ki = 0; ki < Kk; ++ki) {
        const float* vrowp = vbase + (size_t)(si + ki) * (Ww * Cc);
        float4 vr[14];
#pragma unroll
        for (int c = 0; c < 14; ++c) vr[c] = *(const float4*)(vrowp + c * Cc);
        const float* cpk = cbase + ki * 7;
#pragma unroll
        for (int p = 0; p < 8; ++p) {
            const int d = (VAR == 0) ? 0
                        : (VAR == 1) ? -((p < 3) ? p : 3)
                                     : (3 - ((p > 4) ? (p - 4) : 0));
#pragma unroll
            for (int kj = 0; kj < 7; ++kj) {
                const float  cf = cpk[p * (16 * 51) + kj];
                const float4 vv = vr[p + kj + d];
                acc[p][0] += cf * vv.x;
                acc[p][1] += cf * vv.y;
                acc[p][2] += cf * vv.z;
                acc[p][3] += cf * vv.w;
            }
        }
    }
}

__global__ __launch_bounds__(128, 3) void agg_kernel(const float* __restrict__ v,
                                                     const float* __restrict__ attn,
                                                     const float* __restrict__ wgt,
                                                     unsigned short* __restrict__ oh,
                                                     unsigned short* __restrict__ ol)
{
    const int t   = ((blockIdx.x & 7) << 11) | (blockIdx.x >> 3);
    const int b   = t >> 11;
    const int rem = t & 2047;
    const int i   = rem >> 4;
    const int j0  = (rem & 15) << 3;
    const int tid = threadIdx.x;
    const int nh  = tid >> 3;

    __shared__ float coef[8 * 16 * 51];    // 25.5 KB

    const int pixbase = (b << 14) | (i << 7) | j0;
    for (int e = tid; e < 8 * 16 * KK2; e += 128) {
        const int p = e / (16 * KK2);
        const int r = e - p * (16 * KK2);
        const int h = r / KK2;
        const int k = r - h * KK2;
        const float av = __builtin_nontemporal_load(
            attn + ((size_t)(b * NHh + h) * HW + (size_t)((i << 7) | (j0 + p))) * KK2 + k);
        coef[(p * 16 + h) * 51 + k] = av * wgt[(size_t)(pixbase + p) * KK2 + k];
    }

    f32x4 acc[8];
#pragma unroll
    for (int p = 0; p < 8; ++p) acc[p] = (f32x4)0.f;

    const int si = min(max(i - 3, 0), Hh - Kk);
    const int cb = (j0 == 0) ? 0 : ((j0 == 120) ? (Ww - 14) : (j0 - 3));
    const float* vbase = v + ((size_t)b << 23) + ((size_t)cb << 9) + (tid << 2);

    __syncthreads();

    if (j0 == 0)            agg_rows<1>(vbase, coef, si, nh, acc);
    else if (j0 == 120)     agg_rows<2>(vbase, coef, si, nh, acc);
    else                    agg_rows<0>(vbase, coef, si, nh, acc);

#pragma unroll
    for (int p = 0; p < 8; ++p) {
        const size_t o = (size_t)(pixbase + p) * Cc + (size_t)(tid << 2);
        const unsigned short h0 = bf16_rn(acc[p][0]), h1 = bf16_rn(acc[p][1]),
                             h2 = bf16_rn(acc[p][2]), h3 = bf16_rn(acc[p][3]);
        u16x4 hv = {h0, h1, h2, h3};
        u16x4 lv = {bf16_rn(acc[p][0] - bf16_f32(h0)),
                    bf16_rn(acc[p][1] - bf16_f32(h1)),
                    bf16_rn(acc[p][2] - bf16_f32(h2)),
                    bf16_rn(acc[p][3] - bf16_f32(h3))};
        __builtin_nontemporal_store(hv, (u16x4*)(oh + o));
        __builtin_nontemporal_store(lv, (u16x4*)(ol + o));
    }
}

// ----------------------------------------------------------------------------
extern "C" void kernel_launch(void* const* d_in, const int* in_sizes, int n_in,
                              void* d_out, int out_size, void* d_ws, size_t ws_size,
                              hipStream_t stream)
{
    const float* x      = (const float*)d_in[0];
    const float* attn   = (const float*)d_in[1];
    const float* sims   = (const float*)d_in[2];
    const int*   sinds  = (const int*)d_in[3];
    const float* v_w    = (const float*)d_in[4];
    const float* v_b    = (const float*)d_in[5];
    const float* proj_w = (const float*)d_in[6];
    const float* proj_b = (const float*)d_in[7];
    float* out = (float*)d_out;

    char* ws = (char*)d_ws;
    float*          v   = (float*)ws;                                   // 268 MB
    unsigned short* xh  = (unsigned short*)(ws + 268435456);            // 134 MB
    unsigned short* xl  = (unsigned short*)(ws + 268435456 + 134217728);// 134 MB
    float*          wgt = (float*)(ws + 536870912);                     // 25.7 MB
    unsigned short* vwh = (unsigned short*)(ws + 536870912 + 25690112);
    unsigned short* vwl = vwh + 262144;
    unsigned short* pwh = vwl + 262144;
    unsigned short* pwl = pwh + 262144;
    unsigned short* aggh = xh;   // x dead after gemm1
    unsigned short* aggl = xl;

    split_kernel<<<2048, 256, 0, stream>>>(x, xh, xl, Mtot * 512 / 8);
    split_kernel<<<128, 256, 0, stream>>>(v_w, vwh, vwl, 262144 / 8);
    split_kernel<<<128, 256, 0, stream>>>(proj_w, pwh, pwl, 262144 / 8);

    gemm_c3<false><<<4096, 256, 0, stream>>>(xh, xl, vwh, vwl, v_b, v);
    wgt_kernel<<<512, 256, 0, stream>>>(sims, sinds, wgt);
    agg_kernel<<<16384, 128, 0, stream>>>(v, attn, wgt, aggh, aggl);
    gemm_c3<true><<<4096, 256, 0, stream>>>(aggh, aggl, pwh, pwl, proj_b, out);
}